// Round 9
// baseline (49.114 us; speedup 1.0000x reference)
//
#include <hip/hip_runtime.h>

#define IMG 512
#define TW 64
#define TH 32
#define GROWS 38   // GH rows; GH row k = image row ty0-3+k
#define PROWS 42   // HN/HX rows; row r = image row ty0-5+r
#define GST 64     // stride (floats)

__device__ __forceinline__ float nan0(float v){ return v==v ? v : 0.0f; }
__device__ __forceinline__ float min3f(float a,float b,float c){ return fminf(fminf(a,b),c); }
__device__ __forceinline__ float max3f(float a,float b,float c){ return fmaxf(fmaxf(a,b),c); }

__global__ __launch_bounds__(256)
void simplenet_fused(const float* __restrict__ X,
                     const float* __restrict__ w0, const float* __restrict__ b0,
                     const float* __restrict__ w1, const float* __restrict__ w2,
                     const float* __restrict__ w3, const float* __restrict__ w4,
                     const float* __restrict__ w5, const float* __restrict__ w6,
                     float* __restrict__ out)
{
    // LDS holds only h-pass results (cross-thread exchange); raw pixels are
    // re-read from global and served by L1 (8-13KB tile working set).
    __shared__ float GH[GROWS*GST];   //  9728 B gaussH
    __shared__ float HN[PROWS*GST];   // 10752 B h11 min
    __shared__ float HX[PROWS*GST];   // 10752 B h11 max   -> 31232 B total

    const int tid = threadIdx.x;
    const int xo = tid & 63, ty = tid >> 6, y0 = ty*8;   // 8 consecutive rows/thread
    const int bx = blockIdx.x, by = blockIdx.y, bz = blockIdx.z;
    const int tx0 = bx*TW, ty0 = by*TH;
    const bool xe = (bx==0)||(bx==IMG/TW-1);
    const bool ye = (by==0)||(by==IMG/TH-1);
    const float* Xb = X + (size_t)bz*(IMG*IMG);
    const float qn = __builtin_nanf("");

    const float W0c0=w0[0], W0c1=w0[1], B0=b0[0], B1=b0[1];
    const float W1c0=w1[0], W1c1=w1[1], W2c0=w2[0], W2c1=w2[1];
    const float W3c0=w3[0], W3c1=w3[1], W4c0=w4[0], W4c1=w4[1];
    const float W5c0=w5[0], W5c1=w5[1], W6c0=w6[0], W6c1=w6[1];

    const float G0=0.10628875f, G1=0.14032194f, G2=0.16577342f, G3=0.17523179f;

    // ---- producers: 42 rows x 16 col-tasks; global->regs->LDS ----
    for (int t = tid; t < PROWS*16; t += 256) {
        const int r = t >> 4, g = t & 15;
        const int gy  = ty0 - 5 + r;
        const int gx0 = tx0 - 8 + 4*g;          // x[i] <-> global col gx0+i
        float x[20];
        const bool yv = !ye || ((unsigned)gy < IMG);
        if (yv) {
            if (!xe) {
#pragma unroll
                for (int j=0;j<5;++j) {
                    const float4 q = *(const float4*)(Xb + gy*IMG + gx0 + 4*j);
                    x[4*j]=q.x; x[4*j+1]=q.y; x[4*j+2]=q.z; x[4*j+3]=q.w;
                }
            } else {
                const float* row = Xb + gy*IMG;
#pragma unroll
                for (int j=0;j<5;++j) {
                    const int c0 = gx0 + 4*j;
                    if (c0 >= 0 && c0 + 3 < IMG) {
                        const float4 q = *(const float4*)(row + c0);
                        x[4*j]=q.x; x[4*j+1]=q.y; x[4*j+2]=q.z; x[4*j+3]=q.w;
                    } else {
#pragma unroll
                        for (int i=0;i<4;++i) {
                            const int gx = c0 + i;
                            const float v = row[min(max(gx,0),IMG-1)];
                            x[4*j+i] = ((unsigned)gx < IMG) ? v : qn;
                        }
                    }
                }
            }
        } else {
#pragma unroll
            for (int i=0;i<20;++i) x[i] = qn;
        }
        // 3-wide running min/max, center x[i+4]
        float mn[12], mx[12];
#pragma unroll
        for (int i=0;i<12;++i) {
            mn[i] = min3f(x[i+3],x[i+4],x[i+5]);
            mx[i] = max3f(x[i+3],x[i+4],x[i+5]);
        }
        float hn4[4], hx4[4];
#pragma unroll
        for (int k=0;k<4;++k) {                 // 11-window = m3 at offsets 0,3,6,8
            hn4[k] = fminf(fminf(mn[k],mn[k+3]), fminf(mn[k+6],mn[k+8]));
            hx4[k] = fmaxf(fmaxf(mx[k],mx[k+3]), fmaxf(mx[k+6],mx[k+8]));
        }
        *(float4*)&HN[r*GST+4*g] = make_float4(hn4[0],hn4[1],hn4[2],hn4[3]);
        *(float4*)&HX[r*GST+4*g] = make_float4(hx4[0],hx4[1],hx4[2],hx4[3]);
        if (r >= 2 && r < 40) {                 // gaussH only for rows the v-window uses
            float zz[10];
#pragma unroll
            for (int j=0;j<10;++j) zz[j] = xe ? nan0(x[5+j]) : x[5+j];
            float gh4[4];
#pragma unroll
            for (int k=0;k<4;++k)
                gh4[k] = G0*(zz[k]+zz[k+6]) + G1*(zz[k+1]+zz[k+5]) + G2*(zz[k+2]+zz[k+4]) + G3*zz[k+3];
            *(float4*)&GH[(r-2)*GST+4*g] = make_float4(gh4[0],gh4[1],gh4[2],gh4[3]);
        }
    }

    float a0[8], a1[8];

    // ---- trio (identity + 3x3 cross + pool3) straight from global/L1 ----
    {
        const int gxc = tx0 + xo;
        float L[10], C[10], R[10];
        if (!xe && !ye) {
#pragma unroll
            for (int i=0;i<10;++i) {
                const float* row = Xb + (ty0+y0-1+i)*IMG + gxc;
                L[i]=row[-1]; C[i]=row[0]; R[i]=row[1];
            }
        } else {
#pragma unroll
            for (int i=0;i<10;++i) {
                const int gy = ty0+y0-1+i;
                const bool yv = (unsigned)gy < IMG;
                const float* row = Xb + (yv ? gy : 0)*IMG;
                float l = row[max(gxc-1,0)], c = row[gxc], r = row[min(gxc+1,IMG-1)];
                if (!yv) { l=qn; c=qn; r=qn; }
                if (gxc==0)     l=qn;
                if (gxc==IMG-1) r=qn;
                L[i]=l; C[i]=c; R[i]=r;
            }
        }
        float hm[10], hx10[10];
#pragma unroll
        for (int i=0;i<10;++i) { hm[i]=min3f(L[i],C[i],R[i]); hx10[i]=max3f(L[i],C[i],R[i]); }
        float Lz[10], Rz[10];
#pragma unroll
        for (int i=0;i<10;++i) { Lz[i] = xe ? nan0(L[i]) : L[i];
                                 Rz[i] = xe ? nan0(R[i]) : R[i]; }
        const float Cz0 = ye ? nan0(C[0]) : C[0];
        const float Cz9 = ye ? nan0(C[9]) : C[9];
#pragma unroll
        for (int p=0;p<8;++p) {
            const float up = (p==0) ? Cz0 : C[p];
            const float dn = (p==7) ? Cz9 : C[p+2];
            const float cr = 0.25f*(up + dn + Lz[p+1] + Rz[p+1]);
            a0[p] = B0 + W0c0*C[p+1] + W1c0*cr;
            a1[p] = B1 + W0c1*C[p+1] + W1c1*cr;
            const float mnv = min3f(hm[p],hm[p+1],hm[p+2]);
            const float mxv = max3f(hx10[p],hx10[p+1],hx10[p+2]);
            a0[p] += W3c0*mnv + W5c0*mxv;
            a1[p] += W3c1*mnv + W5c1*mxv;
        }
    }
    __syncthreads();

    // ---- gaussV: 14 column reads -> 8 outputs ----
    {
        float wv[14];
#pragma unroll
        for (int i=0;i<14;++i) wv[i] = GH[(y0+i)*GST+xo];
        if (ye) {
#pragma unroll
            for (int i=0;i<14;++i) wv[i] = nan0(wv[i]);
        }
#pragma unroll
        for (int p=0;p<8;++p) {
            const float s = G0*(wv[p]+wv[p+6]) + G1*(wv[p+1]+wv[p+5])
                          + G2*(wv[p+2]+wv[p+4]) + G3*wv[p+3];
            a0[p] += W2c0*s; a1[p] += W2c1*s;
        }
    }

    // ---- v11 van Herk over 18 rows -> 8 outputs ----
    {
        float hn[18], hx[18];
#pragma unroll
        for (int i=0;i<18;++i) { hn[i]=HN[(y0+i)*GST+xo]; hx[i]=HX[(y0+i)*GST+xo]; }
        float sn[11], sx[11];
        sn[10]=hn[10]; sx[10]=hx[10];
#pragma unroll
        for (int i=9;i>=0;--i) { sn[i]=fminf(hn[i],sn[i+1]); sx[i]=fmaxf(hx[i],sx[i+1]); }
        a0[0] += W4c0*sn[0] + W6c0*sx[0];
        a1[0] += W4c1*sn[0] + W6c1*sx[0];
        float pn = hn[11], px = hx[11];
#pragma unroll
        for (int p=1;p<8;++p) {
            const float on = fminf(sn[p], pn);
            const float ox = fmaxf(sx[p], px);
            a0[p] += W4c0*on + W6c0*ox;
            a1[p] += W4c1*on + W6c1*ox;
            if (p<7) { pn = fminf(pn, hn[p+11]); px = fmaxf(px, hx[p+11]); }
        }
    }

    float* o0p = out + ((size_t)bz*2 + 0)*(IMG*IMG) + (size_t)(ty0+y0)*IMG + tx0 + xo;
    float* o1p = o0p + (IMG*IMG);
#pragma unroll
    for (int p=0;p<8;++p) {
        o0p[(size_t)p*IMG] = a0[p];
        o1p[(size_t)p*IMG] = a1[p];
    }
}

extern "C" void kernel_launch(void* const* d_in, const int* in_sizes, int n_in,
                              void* d_out, int out_size, void* d_ws, size_t ws_size,
                              hipStream_t stream) {
    const float* X  = (const float*)d_in[0];
    const float* w0 = (const float*)d_in[1];
    const float* b0 = (const float*)d_in[2];
    const float* w1 = (const float*)d_in[3];
    const float* w2 = (const float*)d_in[4];
    const float* w3 = (const float*)d_in[5];
    const float* w4 = (const float*)d_in[6];
    const float* w5 = (const float*)d_in[7];
    const float* w6 = (const float*)d_in[8];
    float* out = (float*)d_out;

    dim3 grid(IMG/TW, IMG/TH, 32);
    simplenet_fused<<<grid, 256, 0, stream>>>(X, w0, b0, w1, w2, w3, w4, w5, w6, out);
}